// Round 3
// baseline (958.354 us; speedup 1.0000x reference)
//
#include <hip/hip_runtime.h>
#include <hip/hip_bf16.h>

#define DEV __device__ __forceinline__

typedef short bf16x8 __attribute__((ext_vector_type(8)));
typedef float f32x4 __attribute__((ext_vector_type(4)));

static constexpr int BATCH  = 2;
static constexpr int SEQ    = 1024;
static constexpr int DMODEL = 1024;
static constexpr int DINNER = 2048;
static constexpr int DSTATE = 64;
static constexpr int NH     = 32;
static constexpr int HD     = 64;
static constexpr int CONVD  = 2176;
static constexpr int DPROJ  = 4256;
static constexpr int MROWS  = BATCH * SEQ;   // 2048

// ---- workspace layout (bytes) ---- peak ~55.7 MB
// zx: bf16 [2dirs][2048][4256]. After conv, cols 2048.. are dead -> scan
// stores y bf16 into cols 2048..4095 in place. After grms the whole zx is
// dead -> dou (bf16, 8.4MB) aliases ws+0, hb (fp32, 8.4MB) aliases ws+8.4MB.
static constexpr size_t OFF_ZX = 0;
static constexpr size_t OFF_XS = OFF_ZX + (size_t)2*MROWS*DPROJ*2;   // bf16 [4096][2048]; reused as yn
static constexpr size_t OFF_BB = OFF_XS + (size_t)2*MROWS*DINNER*2;  // f32 [4096][64]
static constexpr size_t OFF_CC = OFF_BB + (size_t)2*MROWS*DSTATE*4;  // f32 [4096][64]
static constexpr size_t OFF_DT = OFF_CC + (size_t)2*MROWS*DSTATE*4;  // f32 [4096][32]
static constexpr size_t OFF_DA = OFF_DT + (size_t)2*MROWS*NH*4;      // f32 [4096][32]
static constexpr size_t OFF_DR = OFF_DA + (size_t)2*MROWS*NH*4;      // f32 [4096][32] raw dt (fp32 spill)
static constexpr size_t OFF_DO = 0;                                  // bf16 [4096][1024] (aliases zx)
static constexpr size_t OFF_H  = OFF_DO + (size_t)2*MROWS*DMODEL*2;  // f32  [2048][1024] (aliases zx)

DEV float b2f(ushort u) {
    union { unsigned int i; float f; } v;
    v.i = ((unsigned int)u) << 16;
    return v.f;
}
DEV ushort f2b(float f) {
    union { float f; unsigned int u; } v;
    v.f = f;
    unsigned int r = 0x7FFFu + ((v.u >> 16) & 1u);
    return (ushort)((v.u + r) >> 16);
}

// ---------------------------------------------------------------------------
// GEMM: C[m][n] = sum_k A[m][k] * W[n][k]   (W row-major (N,K), fp32 ->bf16)
// MODE 0: A = x (fp32, per-dir seq flip); out = zxbcdt bf16 (+ fp32 dt spill)
// MODE 1: A = ynorm[dir] (bf16);          out = dirout bf16
// MODE 2: A = concat(dou0, flip(dou1)) (bf16); out = h fp32 + resid + bias
// ---------------------------------------------------------------------------
template<int MODE>
__global__ __launch_bounds__(256) void gemm_k(
    const void* __restrict__ asrc_,
    const float* __restrict__ w0, const float* __restrict__ w1,
    void* __restrict__ outp,
    const float* __restrict__ resid, const float* __restrict__ bias,
    float* __restrict__ dtraw, int N, int K)
{
    constexpr int BM = 128, BN = 64, BK = 32;
    __shared__ ushort As[BM][BK + 8];
    __shared__ ushort Bs[BN][BK + 8];
    const int tid  = threadIdx.x;
    const int wave = tid >> 6, lane = tid & 63;
    const int bn = blockIdx.x * BN, bm = blockIdx.y * BM;
    const int dir = blockIdx.z;
    const float* w = dir ? w1 : w0;

    f32x4 acc[2][4] = {};

    for (int k0 = 0; k0 < K; k0 += BK) {
        // ---- stage A (128x32 bf16 in LDS) ----
        if (MODE == 0) {
            const float* xf = (const float*)asrc_;
            #pragma unroll
            for (int pass = 0; pass < 4; pass++) {
                int idx = pass * 256 + tid;          // 0..1023
                int row = idx >> 3, cg = (idx & 7) * 4;
                int m = bm + row, k = k0 + cg;
                int b = m >> 10, l = m & 1023;
                int ls = dir ? (1023 - l) : l;
                float4 f = *(const float4*)(xf + (size_t)(b * SEQ + ls) * DMODEL + k);
                ushort4 u;
                u.x = f2b(f.x); u.y = f2b(f.y); u.z = f2b(f.z); u.w = f2b(f.w);
                *(ushort4*)&As[row][cg] = u;
            }
        } else {
            const ushort* ab = (const ushort*)asrc_;
            #pragma unroll
            for (int pass = 0; pass < 2; pass++) {
                int idx = pass * 256 + tid;          // 0..511
                int row = idx >> 2, cg = (idx & 3) * 8;
                int m = bm + row, k = k0 + cg;
                const ushort* src;
                if (MODE == 1) {
                    src = ab + ((size_t)(dir * MROWS + m) * DINNER + k);
                } else {
                    if (k < DMODEL) {
                        src = ab + ((size_t)m * DMODEL + k);
                    } else {
                        int l = m & 1023;
                        int m2 = (m & ~1023) | (1023 - l);
                        src = ab + ((size_t)(MROWS + m2) * DMODEL + (k - DMODEL));
                    }
                }
                *(uint4*)&As[row][cg] = *(const uint4*)src;
            }
        }
        // ---- stage B (64x32, fp32 weights -> bf16), guard n < N ----
        #pragma unroll
        for (int pass = 0; pass < 2; pass++) {
            int idx = pass * 256 + tid;              // 0..511
            int row = idx >> 3, cg = (idx & 7) * 4;
            int n = bn + row, k = k0 + cg;
            float4 f = {0.f, 0.f, 0.f, 0.f};
            if (n < N) f = *(const float4*)(w + (size_t)n * K + k);
            ushort4 u;
            u.x = f2b(f.x); u.y = f2b(f.y); u.z = f2b(f.z); u.w = f2b(f.w);
            *(ushort4*)&Bs[row][cg] = u;
        }
        __syncthreads();

        const int ar = wave * 32 + (lane & 15);
        const int ko = (lane >> 4) * 8;
        bf16x8 a0 = *(const bf16x8*)&As[ar][ko];
        bf16x8 a1 = *(const bf16x8*)&As[ar + 16][ko];
        #pragma unroll
        for (int ni = 0; ni < 4; ni++) {
            bf16x8 bfr = *(const bf16x8*)&Bs[ni * 16 + (lane & 15)][ko];
            acc[0][ni] = __builtin_amdgcn_mfma_f32_16x16x32_bf16(a0, bfr, acc[0][ni], 0, 0, 0);
            acc[1][ni] = __builtin_amdgcn_mfma_f32_16x16x32_bf16(a1, bfr, acc[1][ni], 0, 0, 0);
        }
        __syncthreads();
    }

    // epilogue: C/D layout row=(lane>>4)*4+j, col=lane&15
    #pragma unroll
    for (int mi = 0; mi < 2; mi++) {
        #pragma unroll
        for (int ni = 0; ni < 4; ni++) {
            #pragma unroll
            for (int j = 0; j < 4; j++) {
                int row = bm + wave * 32 + mi * 16 + (lane >> 4) * 4 + j;
                int col = bn + ni * 16 + (lane & 15);
                if (col >= N) continue;
                float v = acc[mi][ni][j];
                if (MODE == 0) {
                    ((ushort*)outp)[(size_t)(dir * MROWS + row) * DPROJ + col] = f2b(v);
                    if (col >= 4224)   // fp32 spill of raw dt columns
                        dtraw[(size_t)(dir * MROWS + row) * NH + (col - 4224)] = v;
                } else if (MODE == 1) {
                    ((ushort*)outp)[(size_t)(dir * MROWS + row) * DMODEL + col] = f2b(v);
                } else {
                    float r = resid[(size_t)row * DMODEL + col] + bias[col];
                    ((float*)outp)[(size_t)row * DMODEL + col] = v + r;
                }
            }
        }
    }
}

// ---------------------------------------------------------------------------
// causal depthwise conv(width 4) + bias + SiLU; dt = softplus(raw+bias); dA
// ---------------------------------------------------------------------------
__global__ __launch_bounds__(256) void conv_k(
    const ushort* __restrict__ zx, const float* __restrict__ dtr,
    const float* __restrict__ cw0, const float* __restrict__ cb0,
    const float* __restrict__ cw1, const float* __restrict__ cb1,
    const float* __restrict__ dtb0, const float* __restrict__ al0,
    const float* __restrict__ dtb1, const float* __restrict__ al1,
    ushort* __restrict__ xs, float* __restrict__ Bq, float* __restrict__ Cq,
    float* __restrict__ dtq, float* __restrict__ daq)
{
    int id = blockIdx.x;                 // dir*2048 + m
    int dir = id >> 11;
    int m = id & 2047;
    int l = m & 1023;
    const float* cw = dir ? cw1 : cw0;
    const float* cb = dir ? cb1 : cb0;
    int tid = threadIdx.x;

    for (int c = tid; c < CONVD; c += 256) {
        float acc = cb[c];
        #pragma unroll
        for (int t = 0; t < 4; t++) {
            int ls = l - 3 + t;
            if (ls >= 0) {
                acc += cw[t * CONVD + c] *
                       b2f(zx[(size_t)(id - l + ls) * DPROJ + 2048 + c]);
            }
        }
        float v = acc / (1.f + expf(-acc));   // SiLU
        if (c < DINNER) {
            xs[(size_t)id * DINNER + c] = f2b(v);
        } else if (c < DINNER + DSTATE) {
            Bq[(size_t)id * DSTATE + (c - DINNER)] = v;
        } else {
            Cq[(size_t)id * DSTATE + (c - DINNER - DSTATE)] = v;
        }
    }
    if (tid < NH) {
        const float* dtb = dir ? dtb1 : dtb0;
        const float* al  = dir ? al1 : al0;
        float raw = dtr[(size_t)id * NH + tid] + dtb[tid];
        float dt = raw > 20.f ? raw : log1pf(expf(raw));
        float dA = expf(-expf(al[tid]) * dt);
        dtq[(size_t)id * NH + tid] = dt;
        daq[(size_t)id * NH + tid] = dA;
    }
}

// ---------------------------------------------------------------------------
// sequential SSM scan. grid: (128 = dir*64 + b*32 + h, 4 = p-split), 256 thr.
// thread: p = ps*16 + (tid>>4), owns n in [(tid&15)*4, +4). y via 16-lane shfl.
// y (+ D*x) stored bf16 IN-PLACE into zx cols 2048.. (dead after conv).
// ---------------------------------------------------------------------------
__global__ __launch_bounds__(256) void scan_k(
    const float* __restrict__ Bq, const float* __restrict__ Cq,
    const float* __restrict__ dtq, const float* __restrict__ daq,
    const ushort* __restrict__ xsq,
    const float* __restrict__ D0, const float* __restrict__ D1,
    ushort* __restrict__ yout)
{
    int id = blockIdx.x;
    int dir = id >> 6, b = (id >> 5) & 1, h = id & 31;
    int ps = blockIdx.y;
    int tid = threadIdx.x;
    int p  = ps * 16 + (tid >> 4);
    int nb = (tid & 15) * 4;
    float Dv = (dir ? D1 : D0)[h];
    int base = dir * 2048 + b * 1024;

    float s0 = 0.f, s1 = 0.f, s2 = 0.f, s3 = 0.f;
    for (int l = 0; l < 1024; l++) {
        int r = base + l;
        float dA = daq[(size_t)r * NH + h];
        float dt = dtq[(size_t)r * NH + h];
        float4 Bv = *(const float4*)&Bq[(size_t)r * DSTATE + nb];
        float4 Cv = *(const float4*)&Cq[(size_t)r * DSTATE + nb];
        float xv = b2f(xsq[(size_t)r * DINNER + h * HD + p]);
        float cf = dt * xv;
        s0 = fmaf(s0, dA, cf * Bv.x);
        s1 = fmaf(s1, dA, cf * Bv.y);
        s2 = fmaf(s2, dA, cf * Bv.z);
        s3 = fmaf(s3, dA, cf * Bv.w);
        float part = s0 * Cv.x + s1 * Cv.y + s2 * Cv.z + s3 * Cv.w;
        part += __shfl_xor(part, 1);
        part += __shfl_xor(part, 2);
        part += __shfl_xor(part, 4);
        part += __shfl_xor(part, 8);
        if ((tid & 15) == 0)
            yout[(size_t)r * DPROJ + 2048 + h * HD + p] = f2b(part + Dv * xv);
    }
}

// ---------------------------------------------------------------------------
// gated RMSNorm: g = y * silu(z); g * rsqrt(mean(g^2)+eps) * rms_w -> bf16
// z = zx[:, 0:2048], y = zx[:, 2048:4096] (bf16, written by scan)
// ---------------------------------------------------------------------------
__global__ __launch_bounds__(256) void grms_k(
    const ushort* __restrict__ zx,
    const float* __restrict__ rw0, const float* __restrict__ rw1,
    ushort* __restrict__ yn)
{
    int id = blockIdx.x;
    int dir = id >> 11;
    const float* rw = dir ? rw1 : rw0;
    int tid = threadIdx.x;
    float g[8];
    float ss = 0.f;
    #pragma unroll
    for (int i = 0; i < 8; i++) {
        int c = i * 256 + tid;
        float z  = b2f(zx[(size_t)id * DPROJ + c]);
        float yv = b2f(zx[(size_t)id * DPROJ + 2048 + c]);
        float v = yv * (z / (1.f + expf(-z)));
        g[i] = v;
        ss += v * v;
    }
    for (int o = 32; o; o >>= 1) ss += __shfl_down(ss, o);
    __shared__ float t4[4];
    if ((tid & 63) == 0) t4[tid >> 6] = ss;
    __syncthreads();
    ss = t4[0] + t4[1] + t4[2] + t4[3];
    float sc = rsqrtf(ss * (1.f / DINNER) + 1e-5f);
    #pragma unroll
    for (int i = 0; i < 8; i++) {
        int c = i * 256 + tid;
        yn[(size_t)id * DINNER + c] = f2b(g[i] * sc * rw[c]);
    }
}

// ---------------------------------------------------------------------------
// LayerNorm over 1024 + affine -> fp32 out
// ---------------------------------------------------------------------------
__global__ __launch_bounds__(256) void ln_k(
    const float* __restrict__ h, const float* __restrict__ lw,
    const float* __restrict__ lb, float* __restrict__ out)
{
    int m = blockIdx.x;
    int tid = threadIdx.x;
    float v[4];
    float s = 0.f, s2 = 0.f;
    #pragma unroll
    for (int i = 0; i < 4; i++) {
        int c = i * 256 + tid;
        v[i] = h[(size_t)m * DMODEL + c];
        s += v[i];
        s2 += v[i] * v[i];
    }
    for (int o = 32; o; o >>= 1) { s += __shfl_down(s, o); s2 += __shfl_down(s2, o); }
    __shared__ float ts[4], ts2[4];
    if ((tid & 63) == 0) { ts[tid >> 6] = s; ts2[tid >> 6] = s2; }
    __syncthreads();
    s  = ts[0] + ts[1] + ts[2] + ts[3];
    s2 = ts2[0] + ts2[1] + ts2[2] + ts2[3];
    float mu  = s * (1.f / DMODEL);
    float var = s2 * (1.f / DMODEL) - mu * mu;
    float sc  = rsqrtf(var + 1e-5f);
    #pragma unroll
    for (int i = 0; i < 4; i++) {
        int c = i * 256 + tid;
        out[(size_t)m * DMODEL + c] = (v[i] - mu) * sc * lw[c] + lb[c];
    }
}

extern "C" void kernel_launch(void* const* d_in, const int* in_sizes, int n_in,
                              void* d_out, int out_size, void* d_ws, size_t ws_size,
                              hipStream_t stream)
{
    const float* x     = (const float*)d_in[0];
    const float* f_inw = (const float*)d_in[1];
    const float* f_cw  = (const float*)d_in[2];
    const float* f_cb  = (const float*)d_in[3];
    const float* f_dtb = (const float*)d_in[4];
    const float* f_al  = (const float*)d_in[5];
    const float* f_Dp  = (const float*)d_in[6];
    const float* f_rw  = (const float*)d_in[7];
    const float* f_ow  = (const float*)d_in[8];
    const float* b_inw = (const float*)d_in[9];
    const float* b_cw  = (const float*)d_in[10];
    const float* b_cb  = (const float*)d_in[11];
    const float* b_dtb = (const float*)d_in[12];
    const float* b_al  = (const float*)d_in[13];
    const float* b_Dp  = (const float*)d_in[14];
    const float* b_rw  = (const float*)d_in[15];
    const float* b_ow  = (const float*)d_in[16];
    const float* projw = (const float*)d_in[17];
    const float* projb = (const float*)d_in[18];
    const float* lnw   = (const float*)d_in[19];
    const float* lnb   = (const float*)d_in[20];

    char* ws = (char*)d_ws;
    ushort* zx  = (ushort*)(ws + OFF_ZX);
    ushort* xs  = (ushort*)(ws + OFF_XS);
    float*  Bq  = (float*)(ws + OFF_BB);
    float*  Cq  = (float*)(ws + OFF_CC);
    float*  dtq = (float*)(ws + OFF_DT);
    float*  daq = (float*)(ws + OFF_DA);
    float*  dtr = (float*)(ws + OFF_DR);
    ushort* yn  = (ushort*)(ws + OFF_XS);   // aliases xs (dead after scan)
    ushort* dou = (ushort*)(ws + OFF_DO);   // aliases zx (dead after grms)
    float*  hb  = (float*)(ws + OFF_H);     // aliases zx (dead after grms)

    // K1: in_proj (both dirs), N=4256, K=1024 (+ fp32 dt spill)
    gemm_k<0><<<dim3((DPROJ + 63) / 64, MROWS / 128, 2), 256, 0, stream>>>(
        (const void*)x, f_inw, b_inw, (void*)zx, nullptr, nullptr, dtr, DPROJ, DMODEL);

    // K2: conv + activations + dt/dA
    conv_k<<<dim3(2 * MROWS), 256, 0, stream>>>(
        zx, dtr, f_cw, f_cb, b_cw, b_cb, f_dtb, f_al, b_dtb, b_al,
        xs, Bq, Cq, dtq, daq);

    // K3: sequential scan (writes y bf16 into zx cols 2048..4095)
    scan_k<<<dim3(128, 4), 256, 0, stream>>>(Bq, Cq, dtq, daq, xs, f_Dp, b_Dp, zx);

    // K4: gated RMSNorm (reads z + y from zx, writes yn over xs)
    grms_k<<<dim3(2 * MROWS), 256, 0, stream>>>(zx, f_rw, b_rw, yn);

    // K5: out_proj (both dirs), N=1024, K=2048 (writes dou over zx front)
    gemm_k<1><<<dim3(DMODEL / 64, MROWS / 128, 2), 256, 0, stream>>>(
        (const void*)yn, f_ow, b_ow, (void*)dou, nullptr, nullptr, nullptr, DMODEL, DINNER);

    // K6: final proj + residual + bias, N=1024, K=2048 (fp32 out)
    gemm_k<2><<<dim3(DMODEL / 64, MROWS / 128, 1), 256, 0, stream>>>(
        (const void*)dou, projw, projw, (void*)hb, x, projb, nullptr, DMODEL, DINNER);

    // K7: LayerNorm -> fp32 out
    ln_k<<<dim3(MROWS), 256, 0, stream>>>(hb, lnw, lnb, (float*)d_out);
}